// Round 8
// baseline (4735.849 us; speedup 1.0000x reference)
//
#include <hip/hip_runtime.h>

#define TT 2048
#define HD 64

// LDS arena byte map:
//   h1 : [0, 2048)      parity p, row r at (p*4+r)*256 B; 16B blocks XOR-swizzled
//   h2 : [2112, 4160)   same layout, +64B skew so h1+h2 chunk reads cover all 32 banks
//   fcs: [4160, 5184)
#define H1_BASE 0
#define H2_BASE 2112
#define FCS_BASE 4160

__device__ __forceinline__ float fsig(float x)  { return 1.0f / (1.0f + __expf(-x)); }
__device__ __forceinline__ float ftanh_(float x){ return 1.0f - 2.0f / (1.0f + __expf(2.0f * x)); }

// 16B-block swizzle within a 256B row: block index b in [0,16) -> byte offset
__device__ __forceinline__ int swz(int b) { return ((b ^ ((b >> 2) & 3)) << 4); }

// Explicit AGPR parking (R4-R7: allocator insists on 84 arch VGPRs and parks
// weights itself, paying one v_accvgpr_read per USE (~256/step). We park them
// ourselves and read each back ONCE per step (72 reads), reusing across rows.
#define AWR(dst, src) asm volatile("v_accvgpr_write_b32 %0, %1" : "=a"(dst) : "v"(src))
#define ARD(dst, src) asm volatile("v_accvgpr_read_b32 %0, %1" : "=v"(dst) : "a"(src))

// DPP quad_perm add: pure VALU cross-lane, stays OFF the LDS pipe.
template<int CTRL>
__device__ __forceinline__ float dpp_add(float v) {
    const int o = __builtin_amdgcn_update_dpp(0, __float_as_int(v), CTRL, 0xF, 0xF, true);
    return v + __int_as_float(o);
}
#define BF2D(v) { v = dpp_add<0xB1>(v); v = dpp_add<0x4E>(v); }

// pick row=rk value out of the 4 row-accumulators
#define SEL4(e, x0, x1, x2, x3) \
    float e = x0; e = (rk == 1) ? x1 : e; e = (rk == 2) ? x2 : e; e = (rk == 3) ? x3 : e;

// AGPR weight bank: gate G in {A,B,C,D}, k-block K in {0..3}, comps x..w
#define WDECL_K(G,K) float ag##G##K##x, ag##G##K##y, ag##G##K##z, ag##G##K##w
#define WPARK_K(G,K,V) AWR(ag##G##K##x,(V).x); AWR(ag##G##K##y,(V).y); \
                       AWR(ag##G##K##z,(V).z); AWR(ag##G##K##w,(V).w)
#define WLOAD_K(K) \
    ARD(t0x, agA##K##x); ARD(t0y, agA##K##y); ARD(t0z, agA##K##z); ARD(t0w, agA##K##w); \
    ARD(t1x, agB##K##x); ARD(t1y, agB##K##y); ARD(t1z, agB##K##z); ARD(t1w, agB##K##w); \
    ARD(t2x, agC##K##x); ARD(t2y, agC##K##y); ARD(t2z, agC##K##z); ARD(t2w, agC##K##w); \
    ARD(t3x, agD##K##x); ARD(t3y, agD##K##y); ARD(t3z, agD##K##z); ARD(t3w, agD##K##w)

#define FMAROW(R, HV) \
    a##R##0 = __fmaf_rn(t0x, (HV).x, a##R##0); \
    a##R##1 = __fmaf_rn(t1x, (HV).x, a##R##1); \
    a##R##2 = __fmaf_rn(t2x, (HV).x, a##R##2); \
    a##R##3 = __fmaf_rn(t3x, (HV).x, a##R##3); \
    a##R##0 = __fmaf_rn(t0y, (HV).y, a##R##0); \
    a##R##1 = __fmaf_rn(t1y, (HV).y, a##R##1); \
    a##R##2 = __fmaf_rn(t2y, (HV).y, a##R##2); \
    a##R##3 = __fmaf_rn(t3y, (HV).y, a##R##3); \
    a##R##0 = __fmaf_rn(t0z, (HV).z, a##R##0); \
    a##R##1 = __fmaf_rn(t1z, (HV).z, a##R##1); \
    a##R##2 = __fmaf_rn(t2z, (HV).z, a##R##2); \
    a##R##3 = __fmaf_rn(t3z, (HV).z, a##R##3); \
    a##R##0 = __fmaf_rn(t0w, (HV).w, a##R##0); \
    a##R##1 = __fmaf_rn(t1w, (HV).w, a##R##1); \
    a##R##2 = __fmaf_rn(t2w, (HV).w, a##R##2); \
    a##R##3 = __fmaf_rn(t3w, (HV).w, a##R##3);

// k-block-OUTER, row-inner: weights restored from AGPR once per step,
// reused across all 4 rows (4x fewer accvgpr_reads than per-use).
#define KSTEP(K) { \
    const float4 hv0 = *(const float4*)(rp +   0 + ok##K); \
    const float4 hv1 = *(const float4*)(rp + 256 + ok##K); \
    const float4 hv2 = *(const float4*)(rp + 512 + ok##K); \
    const float4 hv3 = *(const float4*)(rp + 768 + ok##K); \
    float t0x,t0y,t0z,t0w,t1x,t1y,t1z,t1w,t2x,t2y,t2z,t2w,t3x,t3y,t3z,t3w; \
    WLOAD_K(K); \
    FMAROW(0, hv0) FMAROW(1, hv1) FMAROW(2, hv2) FMAROW(3, hv3) }

// Block = 768 threads, 4 batch rows per block, 256 blocks (1 block/CU).
//   waves 0-3  (tid 0..255):   layer0.  j=tid>>2 (unit), ck=tid&3
//   waves 4-11 (tid 256..767): layer1.  p=tid-256, j=p>>3, ck=p&7 ([h1|h2] chunks)
// Pipeline: iter i does layer0 step i and layer1 step i-1; ONE barrier per iter.
__global__ __launch_bounds__(768)
__attribute__((amdgpu_waves_per_eu(3, 3)))
void lstm2_kernel(const float* __restrict__ x,
                  const float* __restrict__ Wih0,
                  const float* __restrict__ Whh0,
                  const float* __restrict__ bih0,
                  const float* __restrict__ bhh0,
                  const float* __restrict__ Wih1,
                  const float* __restrict__ Whh1,
                  const float* __restrict__ bih1,
                  const float* __restrict__ bhh1,
                  const float* __restrict__ fcW,
                  const float* __restrict__ fcb,
                  float* __restrict__ out)
{
    __shared__ __align__(16) float arena_f[1296];
    char* const arena = (char*)arena_f;

    const int tid  = threadIdx.x;
    const int row0 = blockIdx.x * 4;

    const bool isL0 = (tid < 256);
    const int  p    = isL0 ? tid : (tid - 256);
    const int  j    = isL0 ? (p >> 2) : (p >> 3);
    const int  ck   = isL0 ? (p & 3)  : (p & 7);
    const int  ckk  = (ck < 4) ? ck : (ck - 4);
    const int  rk   = ck & 3;                      // this lane's output row

    // ---- AGPR weight bank: 64 weight floats + 4 bias + 4 x-weight ----
    WDECL_K(A,0); WDECL_K(A,1); WDECL_K(A,2); WDECL_K(A,3);
    WDECL_K(B,0); WDECL_K(B,1); WDECL_K(B,2); WDECL_K(B,3);
    WDECL_K(C,0); WDECL_K(C,1); WDECL_K(C,2); WDECL_K(C,3);
    WDECL_K(D,0); WDECL_K(D,1); WDECL_K(D,2); WDECL_K(D,3);
    float agb0, agb1, agb2, agb3, agx0, agx1, agx2, agx3;

    {
        const float* Wsrc;
        if (isL0)        Wsrc = Whh0;
        else if (ck < 4) Wsrc = Wih1;
        else             Wsrc = Whh1;
        const int kbase = 16 * ckk;
        const float4* W0p = (const float4*)(Wsrc + (0 * HD + j) * HD + kbase);
        const float4* W1p = (const float4*)(Wsrc + (1 * HD + j) * HD + kbase);
        const float4* W2p = (const float4*)(Wsrc + (2 * HD + j) * HD + kbase);
        const float4* W3p = (const float4*)(Wsrc + (3 * HD + j) * HD + kbase);
        float4 v;
        v = W0p[0]; WPARK_K(A,0,v);  v = W0p[1]; WPARK_K(A,1,v);
        v = W0p[2]; WPARK_K(A,2,v);  v = W0p[3]; WPARK_K(A,3,v);
        v = W1p[0]; WPARK_K(B,0,v);  v = W1p[1]; WPARK_K(B,1,v);
        v = W1p[2]; WPARK_K(B,2,v);  v = W1p[3]; WPARK_K(B,3,v);
        v = W2p[0]; WPARK_K(C,0,v);  v = W2p[1]; WPARK_K(C,1,v);
        v = W2p[2]; WPARK_K(C,2,v);  v = W2p[3]; WPARK_K(C,3,v);
        v = W3p[0]; WPARK_K(D,0,v);  v = W3p[1]; WPARK_K(D,1,v);
        v = W3p[2]; WPARK_K(D,2,v);  v = W3p[3]; WPARK_K(D,3,v);

        // masked bias / x-weight (only chunk 0 injects them)
        const bool cz = (ck == 0);
        float b0, b1, b2, b3, w0 = 0.f, w1 = 0.f, w2 = 0.f, w3 = 0.f;
        if (isL0) {
            b0 = cz ? (bih0[0*HD+j] + bhh0[0*HD+j]) : 0.f;
            b1 = cz ? (bih0[1*HD+j] + bhh0[1*HD+j]) : 0.f;
            b2 = cz ? (bih0[2*HD+j] + bhh0[2*HD+j]) : 0.f;
            b3 = cz ? (bih0[3*HD+j] + bhh0[3*HD+j]) : 0.f;
            w0 = cz ? Wih0[0*HD+j] : 0.f;
            w1 = cz ? Wih0[1*HD+j] : 0.f;
            w2 = cz ? Wih0[2*HD+j] : 0.f;
            w3 = cz ? Wih0[3*HD+j] : 0.f;
        } else {
            b0 = cz ? (bih1[0*HD+j] + bhh1[0*HD+j]) : 0.f;
            b1 = cz ? (bih1[1*HD+j] + bhh1[1*HD+j]) : 0.f;
            b2 = cz ? (bih1[2*HD+j] + bhh1[2*HD+j]) : 0.f;
            b3 = cz ? (bih1[3*HD+j] + bhh1[3*HD+j]) : 0.f;
        }
        AWR(agb0, b0); AWR(agb1, b1); AWR(agb2, b2); AWR(agb3, b3);
        AWR(agx0, w0); AWR(agx1, w1); AWR(agx2, w2); AWR(agx3, w3);
    }

    // per-thread LDS constants: swizzled k-block offsets, parity read ptrs, store addrs
    const int ok0 = swz(4 * ckk + 0);
    const int ok1 = swz(4 * ckk + 1);
    const int ok2 = swz(4 * ckk + 2);
    const int ok3 = swz(4 * ckk + 3);
    const int rdBufBase = (ck < 4) ? H1_BASE : H2_BASE;
    const int rdPhase   = (ck < 4) ? 1 : 0;
    const char* rpP0 = arena + rdBufBase + ((rdPhase & 1) << 10);        // i even
    const char* rpP1 = arena + rdBufBase + (((1 + rdPhase) & 1) << 10);  // i odd
    const int stBase  = isL0 ? H1_BASE : H2_BASE;
    const int stCore  = stBase + (rk << 8) + swz(j >> 2) + ((j & 3) << 2);
    char* const stP0 = arena + stCore + ((isL0 ? 0 : 1) << 10);          // i even
    char* const stP1 = arena + stCore + ((isL0 ? 1 : 0) << 10);          // i odd

    // zero both parities of h1 and h2
    for (int z = tid; z < 512; z += 768) {
        *(float*)(arena + H1_BASE + 4 * z) = 0.f;
        *(float*)(arena + H2_BASE + 4 * z) = 0.f;
    }

    const float* xp0 = x + (row0 + 0) * TT;
    const float* xp1 = x + (row0 + 1) * TT;
    const float* xp2 = x + (row0 + 2) * TT;
    const float* xp3 = x + (row0 + 3) * TT;
    float xn0 = 0.f, xn1 = 0.f, xn2 = 0.f, xn3 = 0.f;
    if (isL0) { xn0 = xp0[0]; xn1 = xp1[0]; xn2 = xp2[0]; xn3 = xp3[0]; }

    const float fcwj = fcW[j];
    float cc = 0.f, hlast = 0.f;

    __syncthreads();

    for (int i = 0; i <= TT; ++i) {
        const bool odd = (i & 1) != 0;
        const char* rp = odd ? rpP1 : rpP0;

        float a00, a01, a02, a03, a10, a11, a12, a13;
        float a20, a21, a22, a23, a30, a31, a32, a33;

        // ---- acc init from AGPR-parked bias (+ x for layer0) ----
        {
            float bb0, bb1, bb2, bb3;
            ARD(bb0, agb0); ARD(bb1, agb1); ARD(bb2, agb2); ARD(bb3, agb3);
            if (isL0) {
                float xx0, xx1, xx2, xx3;
                ARD(xx0, agx0); ARD(xx1, agx1); ARD(xx2, agx2); ARD(xx3, agx3);
                const float xv0 = xn0, xv1 = xn1, xv2 = xn2, xv3 = xn3;
                const int inext = (i + 1 < TT) ? (i + 1) : (TT - 1);
                xn0 = xp0[inext]; xn1 = xp1[inext]; xn2 = xp2[inext]; xn3 = xp3[inext];
                a00 = __fmaf_rn(xv0, xx0, bb0); a01 = __fmaf_rn(xv0, xx1, bb1);
                a02 = __fmaf_rn(xv0, xx2, bb2); a03 = __fmaf_rn(xv0, xx3, bb3);
                a10 = __fmaf_rn(xv1, xx0, bb0); a11 = __fmaf_rn(xv1, xx1, bb1);
                a12 = __fmaf_rn(xv1, xx2, bb2); a13 = __fmaf_rn(xv1, xx3, bb3);
                a20 = __fmaf_rn(xv2, xx0, bb0); a21 = __fmaf_rn(xv2, xx1, bb1);
                a22 = __fmaf_rn(xv2, xx2, bb2); a23 = __fmaf_rn(xv2, xx3, bb3);
                a30 = __fmaf_rn(xv3, xx0, bb0); a31 = __fmaf_rn(xv3, xx1, bb1);
                a32 = __fmaf_rn(xv3, xx2, bb2); a33 = __fmaf_rn(xv3, xx3, bb3);
            } else {
                a00 = bb0; a01 = bb1; a02 = bb2; a03 = bb3;
                a10 = bb0; a11 = bb1; a12 = bb2; a13 = bb3;
                a20 = bb0; a21 = bb1; a22 = bb2; a23 = bb3;
                a30 = bb0; a31 = bb1; a32 = bb2; a33 = bb3;
            }
        }

        KSTEP(0) KSTEP(1) KSTEP(2) KSTEP(3)

        // intra-quad reduction (xor1 + xor2) on the VALU via DPP quad_perm
        BF2D(a00) BF2D(a01) BF2D(a02) BF2D(a03)
        BF2D(a10) BF2D(a11) BF2D(a12) BF2D(a13)
        BF2D(a20) BF2D(a21) BF2D(a22) BF2D(a23)
        BF2D(a30) BF2D(a31) BF2D(a32) BF2D(a33)

        SEL4(e0, a00, a10, a20, a30)
        SEL4(e1, a01, a11, a21, a31)
        SEL4(e2, a02, a12, a22, a32)
        SEL4(e3, a03, a13, a23, a33)

        if (!isL0) {   // cross-quad combine: quad0 = h1-half, quad1 = h2-half
            e0 += __shfl_xor(e0, 4, 64);
            e1 += __shfl_xor(e1, 4, 64);
            e2 += __shfl_xor(e2, 4, 64);
            e3 += __shfl_xor(e3, 4, 64);
        }

        if (isL0) {
            const float iv = fsig(e0), fv = fsig(e1), gv = ftanh_(e2), ov = fsig(e3);
            cc = __fmaf_rn(fv, cc, iv * gv);
            const float hh = ov * ftanh_(cc);
            *(float*)(odd ? stP1 : stP0) = hh;                 // h1[i]
        } else if (ck < 4 && i > 0) {
            const float iv = fsig(e0), fv = fsig(e1), gv = ftanh_(e2), ov = fsig(e3);
            cc = __fmaf_rn(fv, cc, iv * gv);
            hlast = ov * ftanh_(cc);
            *(float*)(odd ? stP1 : stP0) = hlast;              // h2[i-1]
        }
        __syncthreads();
    }

    // ---- FC: out[row] = sum_j h2[T-1][row][j] * fcW[j] + fcb ----
    if (!isL0 && ck < 4)
        *(float*)(arena + FCS_BASE + ((ck * HD + j) << 2)) = hlast * fcwj;
    __syncthreads();

    if (tid < 64) {
        const int r = tid >> 4, seg = tid & 15;
        const float4 v = ((const float4*)(arena + FCS_BASE))[r * 16 + seg];
        float s = (v.x + v.y) + (v.z + v.w);
        s += __shfl_xor(s, 1, 64);
        s += __shfl_xor(s, 2, 64);
        s += __shfl_xor(s, 4, 64);
        s += __shfl_xor(s, 8, 64);
        if (seg == 0) out[row0 + r] = s + fcb[0];
    }
}

extern "C" void kernel_launch(void* const* d_in, const int* in_sizes, int n_in,
                              void* d_out, int out_size, void* d_ws, size_t ws_size,
                              hipStream_t stream) {
    const float* x    = (const float*)d_in[0];
    const float* Wih0 = (const float*)d_in[1];
    const float* Whh0 = (const float*)d_in[2];
    const float* bih0 = (const float*)d_in[3];
    const float* bhh0 = (const float*)d_in[4];
    const float* Wih1 = (const float*)d_in[5];
    const float* Whh1 = (const float*)d_in[6];
    const float* bih1 = (const float*)d_in[7];
    const float* bhh1 = (const float*)d_in[8];
    const float* fcW  = (const float*)d_in[9];
    const float* fcb  = (const float*)d_in[10];
    float* out = (float*)d_out;

    lstm2_kernel<<<256, 768, 0, stream>>>(x, Wih0, Whh0, bih0, bhh0,
                                          Wih1, Whh1, bih1, bhh1,
                                          fcW, fcb, out);
}